// Round 2
// baseline (695.363 us; speedup 1.0000x reference)
//
#include <hip/hip_runtime.h>

#define KD     3
#define PADV   1
#define DDIM   4        // D = 2*K-2
#define CIN    64
#define COUT   128
#define HH     128
#define WWID   128
#define NN     4
#define KK     9        // K*K
#define OFFC   18       // 2*K*K
#define HW     (HH * WWID)

// ---------------------------------------------------------------------------
// Kernel A: offset field t[n][18][h][w]
//   t[o] = b_off[o] + sum_{c,p} w_off[o,c,p] * (xpad[c, h+ky-1, w+kx-1] - x[c,h,w])
// (center tap p=4 cancels exactly). Block = 256 threads = 4 rows x 64 cols.
// ---------------------------------------------------------------------------
__global__ __launch_bounds__(256, 2)
void offsets_kernel(const float* __restrict__ x, const float* __restrict__ w_off,
                    const float* __restrict__ b_off, float* __restrict__ t) {
  const int n  = blockIdx.z;
  const int h0 = blockIdx.y * 4;
  const int w0 = blockIdx.x * 64;
  const int tid = threadIdx.x;
  const int r  = tid >> 6;     // 0..3
  const int cc = tid & 63;     // 0..63
  const int h = h0 + r;
  const int w = w0 + cc;

  __shared__ float tile[6][66];   // rows h0-1..h0+4, cols w0-1..w0+64

  float acc[OFFC];
#pragma unroll
  for (int o = 0; o < OFFC; ++o) acc[o] = 0.f;

  const float* xn = x + (size_t)n * CIN * HW;

  for (int c = 0; c < CIN; ++c) {
    const float* xc = xn + (size_t)c * HW;
    __syncthreads();   // protect previous iteration's tile reads
    for (int i = tid; i < 6 * 66; i += 256) {
      int tr = i / 66, tc = i % 66;
      int gy = h0 - 1 + tr, gx = w0 - 1 + tc;
      float v = 0.f;
      if (gy >= 0 && gy < HH && gx >= 0 && gx < WWID) v = xc[gy * WWID + gx];
      tile[tr][tc] = v;
    }
    __syncthreads();

    const float center = tile[r + 1][cc + 1];
    float v[KK];
#pragma unroll
    for (int p = 0; p < KK; ++p) {
      const int ky = p / 3, kx = p % 3;
      v[p] = tile[r + ky][cc + kx] - center;   // v[4] == 0
    }

#pragma unroll
    for (int o = 0; o < OFFC; ++o) {
      const float* wrow = w_off + ((size_t)o * CIN + c) * KK;  // uniform -> s_load
      float a = acc[o];
#pragma unroll
      for (int p = 0; p < KK; ++p) {
        if (p == 4) continue;     // center tap cancels
        a += wrow[p] * v[p];
      }
      acc[o] = a;
    }
  }

  float* tn = t + (size_t)n * OFFC * HW;
#pragma unroll
  for (int o = 0; o < OFFC; ++o)
    tn[(size_t)o * HW + h * WWID + w] = acc[o] + b_off[o];
}

// ---------------------------------------------------------------------------
// Kernel B: bilinear deform-sample + depthwise-combine + pointwise, fused.
// 1 thread = 1 output pixel. Per-tap params precomputed with zero-pad
// semantics folded into pre-masked corner weights; all loads clipped
// in-bounds.  acc[128] output accumulators per thread.
// ---------------------------------------------------------------------------
__global__ __launch_bounds__(256, 2)
void deform_pw_kernel(const float* __restrict__ x, const float* __restrict__ t,
                      const float* __restrict__ w_deform, const float* __restrict__ w_pw,
                      float* __restrict__ out) {
  const int n  = blockIdx.z;
  const int h0 = blockIdx.y * 4;
  const int w0 = blockIdx.x * 64;
  const int tid = threadIdx.x;
  const int r  = tid >> 6;
  const int cc = tid & 63;
  const int h = h0 + r;
  const int w = w0 + cc;

  const float* xn = x + (size_t)n * CIN * HW;
  const float* tn = t + (size_t)n * OFFC * HW;
  const int pix = h * WWID + w;

  // Per-tap precompute: 4 clipped corner indices + 4 pre-masked bilinear weights
  int   i00[KK], i01[KK], i10[KK], i11[KK];
  float c00[KK], c01[KK], c10[KK], c11[KK];
#pragma unroll
  for (int p = 0; p < KK; ++p) {
    const int ky = p / 3, kx = p % 3;
    const float dy = tn[(size_t)(2 * p)     * HW + pix];
    const float dx = tn[(size_t)(2 * p + 1) * HW + pix];
    const float py = dy + (float)(h + ky - PADV);
    const float px = dx + (float)(w + kx - PADV);
    const float fy = floorf(py), fx = floorf(px);
    const int y0 = (int)fy,  x0 = (int)fx;
    const int y1 = y0 + 1,   x1 = x0 + 1;
    const float ay = py - fy, ax = px - fx;
    const bool vy0 = (y0 >= 0) && (y0 < HH);
    const bool vy1 = (y1 >= 0) && (y1 < HH);
    const bool vx0 = (x0 >= 0) && (x0 < WWID);
    const bool vx1 = (x1 >= 0) && (x1 < WWID);
    const int yc0 = min(max(y0, 0), HH - 1),  yc1 = min(max(y1, 0), HH - 1);
    const int xc0 = min(max(x0, 0), WWID - 1), xc1 = min(max(x1, 0), WWID - 1);
    i00[p] = yc0 * WWID + xc0;  i01[p] = yc0 * WWID + xc1;
    i10[p] = yc1 * WWID + xc0;  i11[p] = yc1 * WWID + xc1;
    c00[p] = (vy0 && vx0) ? (1.f - ay) * (1.f - ax) : 0.f;
    c01[p] = (vy0 && vx1) ? (1.f - ay) * ax         : 0.f;
    c10[p] = (vy1 && vx0) ? ay * (1.f - ax)         : 0.f;
    c11[p] = (vy1 && vx1) ? ay * ax                 : 0.f;
  }

  float acc[COUT];
#pragma unroll
  for (int o = 0; o < COUT; ++o) acc[o] = 0.f;

  for (int c = 0; c < CIN; ++c) {
    const float* xc = xn + (size_t)c * HW;
    const float xcv = xc[pix];
    float yd0 = 0.f, yd1 = 0.f, yd2 = 0.f, yd3 = 0.f;
#pragma unroll
    for (int p = 0; p < KK; ++p) {
      const float samp = c00[p] * xc[i00[p]] + c01[p] * xc[i01[p]]
                       + c10[p] * xc[i10[p]] + c11[p] * xc[i11[p]];
      const float s = samp - xcv;
      const float* wdp = w_deform + ((size_t)c * DDIM) * KK + p;  // uniform -> s_load
      yd0 += wdp[0 * KK] * s;
      yd1 += wdp[1 * KK] * s;
      yd2 += wdp[2 * KK] * s;
      yd3 += wdp[3 * KK] * s;
    }
    const float* wp = w_pw + c * DDIM;   // uniform base
#pragma unroll
    for (int o = 0; o < COUT; ++o) {
      const float* wpo = wp + (size_t)o * (CIN * DDIM);  // 16B-aligned -> s_load_dwordx4
      acc[o] += wpo[0] * yd0 + wpo[1] * yd1 + wpo[2] * yd2 + wpo[3] * yd3;
    }
  }

  float* on = out + (size_t)n * COUT * HW;
#pragma unroll
  for (int o = 0; o < COUT; ++o)
    on[(size_t)o * HW + pix] = acc[o];
}

// ---------------------------------------------------------------------------
extern "C" void kernel_launch(void* const* d_in, const int* in_sizes, int n_in,
                              void* d_out, int out_size, void* d_ws, size_t ws_size,
                              hipStream_t stream) {
  const float* x        = (const float*)d_in[0];
  const float* w_off    = (const float*)d_in[1];
  const float* b_off    = (const float*)d_in[2];
  const float* w_deform = (const float*)d_in[3];
  const float* w_pw     = (const float*)d_in[4];
  float* out = (float*)d_out;
  float* t   = (float*)d_ws;   // N*18*H*W fp32 = 4.5 MB

  dim3 grid(WWID / 64, HH / 4, NN);
  dim3 block(256);
  offsets_kernel<<<grid, block, 0, stream>>>(x, w_off, b_off, t);
  deform_pw_kernel<<<grid, block, 0, stream>>>(x, t, w_deform, w_pw, out);
}

// Round 3
// 298.155 us; speedup vs baseline: 2.3322x; 2.3322x over previous
//
#include <hip/hip_runtime.h>

#define KD     3
#define PADV   1
#define DDIM   4        // D = 2*K-2
#define CIN    64
#define COUT   128
#define CDIM   256      // CIN*DDIM
#define HH     128
#define WWID   128
#define NN     4
#define KK     9        // K*K
#define OFFC   18       // 2*K*K
#define HW     (HH * WWID)

typedef __attribute__((ext_vector_type(8))) short bf16x8;
typedef __attribute__((ext_vector_type(4))) float f32x4;

__device__ __forceinline__ unsigned short f2bf(float f) {
  union { float f; unsigned u; } c; c.f = f;
  unsigned u = c.u;
  return (unsigned short)((u + 0x7FFFu + ((u >> 16) & 1u)) >> 16);  // RNE
}

// ---------------------------------------------------------------------------
// Kernel 0: convert w_pw (128x256 fp32) -> bf16 in ws
// ---------------------------------------------------------------------------
__global__ void convert_wpw(const float* __restrict__ w_pw, unsigned short* __restrict__ wbf) {
  int i = blockIdx.x * 256 + threadIdx.x;
  if (i < COUT * CDIM) wbf[i] = f2bf(w_pw[i]);
}

// ---------------------------------------------------------------------------
// Kernel A: offset field t[n][18][h][w], c split 4-ways across blocks,
// partials accumulated with fp32 atomicAdd into zero-initialized t.
// Block = 256 threads = 4 rows x 64 cols; grid (2, 32, NN*4).
// ---------------------------------------------------------------------------
__global__ __launch_bounds__(256, 4)
void offsets_kernel(const float* __restrict__ x, const float* __restrict__ w_off,
                    const float* __restrict__ b_off, float* __restrict__ t) {
  const int n     = blockIdx.z >> 2;
  const int chunk = blockIdx.z & 3;        // 16 channels per chunk
  const int h0 = blockIdx.y * 4;
  const int w0 = blockIdx.x * 64;
  const int tid = threadIdx.x;
  const int r  = tid >> 6;
  const int cc = tid & 63;
  const int h = h0 + r;
  const int w = w0 + cc;

  __shared__ float tile[6][66];

  float acc[OFFC];
#pragma unroll
  for (int o = 0; o < OFFC; ++o) acc[o] = 0.f;

  const float* xn = x + (size_t)n * CIN * HW;

  for (int ci = 0; ci < CIN / 4; ++ci) {
    const int c = chunk * (CIN / 4) + ci;
    const float* xc = xn + (size_t)c * HW;
    __syncthreads();
    for (int i = tid; i < 6 * 66; i += 256) {
      int tr = i / 66, tc = i % 66;
      int gy = h0 - 1 + tr, gx = w0 - 1 + tc;
      float v = 0.f;
      if (gy >= 0 && gy < HH && gx >= 0 && gx < WWID) v = xc[gy * WWID + gx];
      tile[tr][tc] = v;
    }
    __syncthreads();

    const float center = tile[r + 1][cc + 1];
    float v[KK];
#pragma unroll
    for (int p = 0; p < KK; ++p)
      v[p] = tile[r + p / 3][cc + p % 3] - center;   // v[4] == 0

#pragma unroll
    for (int o = 0; o < OFFC; ++o) {
      const float* wrow = w_off + ((size_t)o * CIN + c) * KK;  // wave-uniform
      float a = acc[o];
#pragma unroll
      for (int p = 0; p < KK; ++p) {
        if (p == 4) continue;
        a += wrow[p] * v[p];
      }
      acc[o] = a;
    }
  }

  float* tn = t + (size_t)n * OFFC * HW;
  const int pix = h * WWID + w;
#pragma unroll
  for (int o = 0; o < OFFC; ++o) {
    float contrib = acc[o] + (chunk == 0 ? b_off[o] : 0.f);
    atomicAdd(tn + (size_t)o * HW + pix, contrib);
  }
}

// ---------------------------------------------------------------------------
// Kernel B: fused bilinear sample + depthwise + MFMA pointwise.
// Block = 256 threads = 4 waves; 64-pixel strip.
// Phase 1: wave cg computes y[pix][c*4+d] for c in [cg*16, cg*16+16) -> LDS
//          (bf16, 16B-chunk XOR swizzle to kill phase-2 bank conflicts).
// Phase 2: out(128 x 64 strip) = w_pw_bf16(128x256) . y(64x256)^T via
//          mfma_f32_16x16x32_bf16; wave -> 64(M) x 32(N) sub-tile.
// ---------------------------------------------------------------------------
__global__ __launch_bounds__(256, 3)
void fused_deform_pw(const float* __restrict__ x, const float* __restrict__ t,
                     const float* __restrict__ w_deform,
                     const unsigned short* __restrict__ wbf,
                     float* __restrict__ out) {
  const int bx = blockIdx.x;              // 0..1023
  const int n = bx >> 8;
  const int pixbase = (bx & 255) * 64;
  const int tid = threadIdx.x;
  const int pl = tid & 63;                // pixel within strip (== lane)
  const int cg = tid >> 6;                // wave id == channel group
  const int pix = pixbase + pl;
  const int h = pix >> 7;
  const int w = pix & 127;

  __shared__ unsigned short ylds[64][CDIM];   // 32 KB, swizzled storage

  const float* xn = x + (size_t)n * CIN * HW;
  const float* tn = t + (size_t)n * OFFC * HW;

  // ---- per-pixel tap params (pre-masked bilinear corner weights) ----
  int   i00[KK], i01[KK], i10[KK], i11[KK];
  float c00[KK], c01[KK], c10[KK], c11[KK];
#pragma unroll
  for (int p = 0; p < KK; ++p) {
    const int ky = p / 3, kx = p % 3;
    const float dy = tn[(size_t)(2 * p)     * HW + pix];
    const float dx = tn[(size_t)(2 * p + 1) * HW + pix];
    const float py = dy + (float)(h + ky - PADV);
    const float px = dx + (float)(w + kx - PADV);
    const float fy = floorf(py), fx = floorf(px);
    const int y0 = (int)fy,  x0 = (int)fx;
    const int y1 = y0 + 1,   x1 = x0 + 1;
    const float ay = py - fy, ax = px - fx;
    const bool vy0 = (y0 >= 0) && (y0 < HH);
    const bool vy1 = (y1 >= 0) && (y1 < HH);
    const bool vx0 = (x0 >= 0) && (x0 < WWID);
    const bool vx1 = (x1 >= 0) && (x1 < WWID);
    const int yc0 = min(max(y0, 0), HH - 1),  yc1 = min(max(y1, 0), HH - 1);
    const int xc0 = min(max(x0, 0), WWID - 1), xc1 = min(max(x1, 0), WWID - 1);
    i00[p] = yc0 * WWID + xc0;  i01[p] = yc0 * WWID + xc1;
    i10[p] = yc1 * WWID + xc0;  i11[p] = yc1 * WWID + xc1;
    c00[p] = (vy0 && vx0) ? (1.f - ay) * (1.f - ax) : 0.f;
    c01[p] = (vy0 && vx1) ? (1.f - ay) * ax         : 0.f;
    c10[p] = (vy1 && vx0) ? ay * (1.f - ax)         : 0.f;
    c11[p] = (vy1 && vx1) ? ay * ax                 : 0.f;
  }

  // ---- phase 1: y for 16 channels of this wave's group ----
  for (int ci = 0; ci < CIN / 4; ++ci) {
    const int c = cg * (CIN / 4) + ci;
    const float* xc = xn + (size_t)c * HW;
    const float xcv = xc[pix];
    float yd0 = 0.f, yd1 = 0.f, yd2 = 0.f, yd3 = 0.f;
#pragma unroll
    for (int p = 0; p < KK; ++p) {
      const float samp = c00[p] * xc[i00[p]] + c01[p] * xc[i01[p]]
                       + c10[p] * xc[i10[p]] + c11[p] * xc[i11[p]];
      const float s = samp - xcv;
      const float* wdp = w_deform + (size_t)(c * DDIM) * KK + p;  // wave-uniform
      yd0 += wdp[0 * KK] * s;
      yd1 += wdp[1 * KK] * s;
      yd2 += wdp[2 * KK] * s;
      yd3 += wdp[3 * KK] * s;
    }
    // pack 4 bf16 and store swizzled: element e stored at ((e>>3)^(pl&7))<<3 | (e&7)
    unsigned lo = (unsigned)f2bf(yd0) | ((unsigned)f2bf(yd1) << 16);
    unsigned hi = (unsigned)f2bf(yd2) | ((unsigned)f2bf(yd3) << 16);
    const int ebase = (((c >> 1) ^ (pl & 7)) << 3) + (c & 1) * 4;
    uint2* dst = reinterpret_cast<uint2*>(&ylds[pl][ebase]);
    *dst = make_uint2(lo, hi);
  }
  __syncthreads();

  // ---- phase 2: MFMA pointwise ----
  const int wave = tid >> 6;
  const int l15 = tid & 15;
  const int kg  = (tid & 63) >> 4;
  const int Mb = (wave >> 1) * 64;     // output-channel base for this wave
  const int Nb = (wave & 1) * 32;      // pixel base (within strip)

  f32x4 acc[4][2];
#pragma unroll
  for (int mi = 0; mi < 4; ++mi)
#pragma unroll
    for (int ni = 0; ni < 2; ++ni)
      acc[mi][ni] = (f32x4){0.f, 0.f, 0.f, 0.f};

#pragma unroll
  for (int ks = 0; ks < 8; ++ks) {     // K = 256 in steps of 32
    bf16x8 bfr[2];
#pragma unroll
    for (int ni = 0; ni < 2; ++ni) {
      const int prow = Nb + ni * 16 + l15;
      const int chunk = ks * 4 + kg;
      const int eb = ((chunk ^ (prow & 7)) << 3);
      bfr[ni] = *reinterpret_cast<const bf16x8*>(&ylds[prow][eb]);
    }
    bf16x8 afr[4];
#pragma unroll
    for (int mi = 0; mi < 4; ++mi) {
      const int o = Mb + mi * 16 + l15;
      afr[mi] = *reinterpret_cast<const bf16x8*>(wbf + (size_t)o * CDIM + ks * 32 + kg * 8);
    }
#pragma unroll
    for (int mi = 0; mi < 4; ++mi)
#pragma unroll
      for (int ni = 0; ni < 2; ++ni)
        acc[mi][ni] = __builtin_amdgcn_mfma_f32_16x16x32_bf16(afr[mi], bfr[ni], acc[mi][ni], 0, 0, 0);
  }

  // ---- epilogue: C/D layout col=lane&15, row=(lane>>4)*4+reg ----
  float* on = out + (size_t)n * COUT * HW;
#pragma unroll
  for (int mi = 0; mi < 4; ++mi) {
#pragma unroll
    for (int ni = 0; ni < 2; ++ni) {
      const int pcol = pixbase + Nb + ni * 16 + l15;
#pragma unroll
      for (int reg = 0; reg < 4; ++reg) {
        const int o = Mb + mi * 16 + kg * 4 + reg;
        on[(size_t)o * HW + pcol] = acc[mi][ni][reg];
      }
    }
  }
}

// ---------------------------------------------------------------------------
extern "C" void kernel_launch(void* const* d_in, const int* in_sizes, int n_in,
                              void* d_out, int out_size, void* d_ws, size_t ws_size,
                              hipStream_t stream) {
  const float* x        = (const float*)d_in[0];
  const float* w_off    = (const float*)d_in[1];
  const float* b_off    = (const float*)d_in[2];
  const float* w_deform = (const float*)d_in[3];
  const float* w_pw     = (const float*)d_in[4];
  float* out = (float*)d_out;

  float* t = (float*)d_ws;                                   // 4*18*16384*4 = 4718592 B
  unsigned short* wbf = (unsigned short*)((char*)d_ws + 4718592);  // 65536 B

  hipMemsetAsync(t, 0, (size_t)NN * OFFC * HW * sizeof(float), stream);
  convert_wpw<<<dim3((COUT * CDIM + 255) / 256), dim3(256), 0, stream>>>(w_pw, wbf);
  offsets_kernel<<<dim3(WWID / 64, HH / 4, NN * 4), dim3(256), 0, stream>>>(x, w_off, b_off, t);
  fused_deform_pw<<<dim3(NN * HW / 64), dim3(256), 0, stream>>>(x, t, w_deform, wbf, out);
}

// Round 4
// 282.737 us; speedup vs baseline: 2.4594x; 1.0545x over previous
//
#include <hip/hip_runtime.h>

#define KD     3
#define PADV   1
#define DDIM   4        // D = 2*K-2
#define CIN    64
#define COUT   128
#define CDIM   256      // CIN*DDIM
#define HH     128
#define WWID   128
#define NN     4
#define KK     9        // K*K
#define OFFC   18       // 2*K*K
#define HW     (HH * WWID)

typedef __attribute__((ext_vector_type(8))) short bf16x8;
typedef __attribute__((ext_vector_type(4))) float f32x4;

__device__ __forceinline__ unsigned short f2bf(float f) {
  union { float f; unsigned u; } c; c.f = f;
  unsigned u = c.u;
  return (unsigned short)((u + 0x7FFFu + ((u >> 16) & 1u)) >> 16);  // RNE
}

// ---------------------------------------------------------------------------
// Kernel 0: convert w_pw (128x256 fp32) -> bf16 in ws
// ---------------------------------------------------------------------------
__global__ void convert_wpw(const float* __restrict__ w_pw, unsigned short* __restrict__ wbf) {
  int i = blockIdx.x * 256 + threadIdx.x;
  if (i < COUT * CDIM) wbf[i] = f2bf(w_pw[i]);
}

// ---------------------------------------------------------------------------
// Kernel A: offset field t[n][18][h][w], c split 8-ways across blocks,
// partials accumulated with fp32 atomicAdd into zero-initialized t.
// Block = 256 threads = 4 rows x 64 cols; grid (2, 32, NN*8) = 2048 blocks.
// ---------------------------------------------------------------------------
__global__ __launch_bounds__(256, 4)
void offsets_kernel(const float* __restrict__ x, const float* __restrict__ w_off,
                    const float* __restrict__ b_off, float* __restrict__ t) {
  const int n     = blockIdx.z >> 3;
  const int chunk = blockIdx.z & 7;        // 8 channels per chunk
  const int h0 = blockIdx.y * 4;
  const int w0 = blockIdx.x * 64;
  const int tid = threadIdx.x;
  const int r  = tid >> 6;
  const int cc = tid & 63;
  const int h = h0 + r;
  const int w = w0 + cc;

  __shared__ float tile[6][66];

  float acc[OFFC];
#pragma unroll
  for (int o = 0; o < OFFC; ++o) acc[o] = 0.f;

  const float* xn = x + (size_t)n * CIN * HW;

  for (int ci = 0; ci < CIN / 8; ++ci) {
    const int c = chunk * (CIN / 8) + ci;
    const float* xc = xn + (size_t)c * HW;
    __syncthreads();
    for (int i = tid; i < 6 * 66; i += 256) {
      int tr = i / 66, tc = i % 66;
      int gy = h0 - 1 + tr, gx = w0 - 1 + tc;
      float v = 0.f;
      if (gy >= 0 && gy < HH && gx >= 0 && gx < WWID) v = xc[gy * WWID + gx];
      tile[tr][tc] = v;
    }
    __syncthreads();

    const float center = tile[r + 1][cc + 1];
    float v[KK];
#pragma unroll
    for (int p = 0; p < KK; ++p)
      v[p] = tile[r + p / 3][cc + p % 3] - center;   // v[4] == 0

#pragma unroll
    for (int o = 0; o < OFFC; ++o) {
      const float* wrow = w_off + ((size_t)o * CIN + c) * KK;  // wave-uniform
      float a = acc[o];
#pragma unroll
      for (int p = 0; p < KK; ++p) {
        if (p == 4) continue;
        a += wrow[p] * v[p];
      }
      acc[o] = a;
    }
  }

  float* tn = t + (size_t)n * OFFC * HW;
  const int pix = h * WWID + w;
#pragma unroll
  for (int o = 0; o < OFFC; ++o) {
    float contrib = acc[o] + (chunk == 0 ? b_off[o] : 0.f);
    atomicAdd(tn + (size_t)o * HW + pix, contrib);
  }
}

// ---------------------------------------------------------------------------
// Kernel B: fused bilinear sample + depthwise + MFMA pointwise.
// Block = 512 threads = 8 waves; 64-pixel strip.
// Phase 1: wave cg computes y[pix][c*4+d] for c in [cg*8, cg*8+8) -> LDS
//          (bf16, 16B-chunk XOR swizzle).
// Phase 2: out(128 x 64 strip) = w_pw_bf16(128x256) . y(64x256)^T via
//          mfma_f32_16x16x32_bf16; wave -> 32(M) x 32(N) sub-tile.
// ---------------------------------------------------------------------------
__global__ __launch_bounds__(512, 4)
void fused_deform_pw(const float* __restrict__ x, const float* __restrict__ t,
                     const float* __restrict__ w_deform,
                     const unsigned short* __restrict__ wbf,
                     float* __restrict__ out) {
  const int bx = blockIdx.x;              // 0..1023
  const int n = bx >> 8;
  const int pixbase = (bx & 255) * 64;
  const int tid = threadIdx.x;
  const int pl = tid & 63;                // pixel within strip (== lane)
  const int cg = tid >> 6;                // wave id == channel group (0..7)
  const int pix = pixbase + pl;
  const int h = pix >> 7;
  const int w = pix & 127;

  __shared__ unsigned short ylds[64][CDIM];   // 32 KB, swizzled storage

  const float* xn = x + (size_t)n * CIN * HW;
  const float* tn = t + (size_t)n * OFFC * HW;

  // ---- per-pixel tap params (pre-masked bilinear corner weights) ----
  int   i00[KK], i01[KK], i10[KK], i11[KK];
  float c00[KK], c01[KK], c10[KK], c11[KK];
#pragma unroll
  for (int p = 0; p < KK; ++p) {
    const int ky = p / 3, kx = p % 3;
    const float dy = tn[(size_t)(2 * p)     * HW + pix];
    const float dx = tn[(size_t)(2 * p + 1) * HW + pix];
    const float py = dy + (float)(h + ky - PADV);
    const float px = dx + (float)(w + kx - PADV);
    const float fy = floorf(py), fx = floorf(px);
    const int y0 = (int)fy,  x0 = (int)fx;
    const int y1 = y0 + 1,   x1 = x0 + 1;
    const float ay = py - fy, ax = px - fx;
    const bool vy0 = (y0 >= 0) && (y0 < HH);
    const bool vy1 = (y1 >= 0) && (y1 < HH);
    const bool vx0 = (x0 >= 0) && (x0 < WWID);
    const bool vx1 = (x1 >= 0) && (x1 < WWID);
    const int yc0 = min(max(y0, 0), HH - 1),  yc1 = min(max(y1, 0), HH - 1);
    const int xc0 = min(max(x0, 0), WWID - 1), xc1 = min(max(x1, 0), WWID - 1);
    i00[p] = yc0 * WWID + xc0;  i01[p] = yc0 * WWID + xc1;
    i10[p] = yc1 * WWID + xc0;  i11[p] = yc1 * WWID + xc1;
    c00[p] = (vy0 && vx0) ? (1.f - ay) * (1.f - ax) : 0.f;
    c01[p] = (vy0 && vx1) ? (1.f - ay) * ax         : 0.f;
    c10[p] = (vy1 && vx0) ? ay * (1.f - ax)         : 0.f;
    c11[p] = (vy1 && vx1) ? ay * ax                 : 0.f;
  }

  // ---- phase 1: y for 8 channels of this wave's group ----
  for (int ci = 0; ci < CIN / 8; ++ci) {
    const int c = cg * (CIN / 8) + ci;
    const float* xc = xn + (size_t)c * HW;
    const float xcv = xc[pix];
    float yd0 = 0.f, yd1 = 0.f, yd2 = 0.f, yd3 = 0.f;
#pragma unroll
    for (int p = 0; p < KK; ++p) {
      const float samp = c00[p] * xc[i00[p]] + c01[p] * xc[i01[p]]
                       + c10[p] * xc[i10[p]] + c11[p] * xc[i11[p]];
      const float s = samp - xcv;
      const float* wdp = w_deform + (size_t)(c * DDIM) * KK + p;  // wave-uniform
      yd0 += wdp[0 * KK] * s;
      yd1 += wdp[1 * KK] * s;
      yd2 += wdp[2 * KK] * s;
      yd3 += wdp[3 * KK] * s;
    }
    // pack 4 bf16, store swizzled: chunk (c>>1) at ((c>>1)^(pl&7))<<3, half (c&1)
    unsigned lo = (unsigned)f2bf(yd0) | ((unsigned)f2bf(yd1) << 16);
    unsigned hi = (unsigned)f2bf(yd2) | ((unsigned)f2bf(yd3) << 16);
    const int ebase = (((c >> 1) ^ (pl & 7)) << 3) + (c & 1) * 4;
    uint2* dst = reinterpret_cast<uint2*>(&ylds[pl][ebase]);
    *dst = make_uint2(lo, hi);
  }
  __syncthreads();

  // ---- phase 2: MFMA pointwise; 8 waves -> 4(M) x 2(N) grid of 32x32 tiles ----
  const int wave = tid >> 6;
  const int l15 = tid & 15;
  const int kg  = (tid & 63) >> 4;
  const int Mb = (wave >> 1) * 32;     // output-channel base for this wave
  const int Nb = (wave & 1) * 32;      // pixel base (within strip)

  f32x4 acc[2][2];
#pragma unroll
  for (int mi = 0; mi < 2; ++mi)
#pragma unroll
    for (int ni = 0; ni < 2; ++ni)
      acc[mi][ni] = (f32x4){0.f, 0.f, 0.f, 0.f};

#pragma unroll
  for (int ks = 0; ks < 8; ++ks) {     // K = 256 in steps of 32
    bf16x8 bfr[2];
#pragma unroll
    for (int ni = 0; ni < 2; ++ni) {
      const int prow = Nb + ni * 16 + l15;
      const int chunk = ks * 4 + kg;
      const int eb = ((chunk ^ (prow & 7)) << 3);
      bfr[ni] = *reinterpret_cast<const bf16x8*>(&ylds[prow][eb]);
    }
    bf16x8 afr[2];
#pragma unroll
    for (int mi = 0; mi < 2; ++mi) {
      const int o = Mb + mi * 16 + l15;
      afr[mi] = *reinterpret_cast<const bf16x8*>(wbf + (size_t)o * CDIM + ks * 32 + kg * 8);
    }
#pragma unroll
    for (int mi = 0; mi < 2; ++mi)
#pragma unroll
      for (int ni = 0; ni < 2; ++ni)
        acc[mi][ni] = __builtin_amdgcn_mfma_f32_16x16x32_bf16(afr[mi], bfr[ni], acc[mi][ni], 0, 0, 0);
  }

  // ---- epilogue: C/D layout col=lane&15, row=(lane>>4)*4+reg ----
  float* on = out + (size_t)n * COUT * HW;
#pragma unroll
  for (int mi = 0; mi < 2; ++mi) {
#pragma unroll
    for (int ni = 0; ni < 2; ++ni) {
      const int pcol = pixbase + Nb + ni * 16 + l15;
#pragma unroll
      for (int reg = 0; reg < 4; ++reg) {
        const int o = Mb + mi * 16 + kg * 4 + reg;
        on[(size_t)o * HW + pcol] = acc[mi][ni][reg];
      }
    }
  }
}

// ---------------------------------------------------------------------------
extern "C" void kernel_launch(void* const* d_in, const int* in_sizes, int n_in,
                              void* d_out, int out_size, void* d_ws, size_t ws_size,
                              hipStream_t stream) {
  const float* x        = (const float*)d_in[0];
  const float* w_off    = (const float*)d_in[1];
  const float* b_off    = (const float*)d_in[2];
  const float* w_deform = (const float*)d_in[3];
  const float* w_pw     = (const float*)d_in[4];
  float* out = (float*)d_out;

  float* t = (float*)d_ws;                                   // 4*18*16384*4 = 4718592 B
  unsigned short* wbf = (unsigned short*)((char*)d_ws + 4718592);  // 65536 B

  hipMemsetAsync(t, 0, (size_t)NN * OFFC * HW * sizeof(float), stream);
  convert_wpw<<<dim3((COUT * CDIM + 255) / 256), dim3(256), 0, stream>>>(w_pw, wbf);
  offsets_kernel<<<dim3(WWID / 64, HH / 4, NN * 8), dim3(256), 0, stream>>>(x, w_off, b_off, t);
  fused_deform_pw<<<dim3(NN * HW / 64), dim3(512), 0, stream>>>(x, t, w_deform, wbf, out);
}

// Round 5
// 179.068 us; speedup vs baseline: 3.8832x; 1.5789x over previous
//
#include <hip/hip_runtime.h>

#define DDIM   4        // D = 2*K-2
#define CIN    64
#define COUT   128
#define CDIM   256      // CIN*DDIM
#define HH     128
#define WWID   128
#define NN     4
#define KK     9        // K*K
#define OFFC   18       // 2*K*K
#define HW     (HH * WWID)

// ---- LDS layout (floats) ----
#define XS_COLS   73                        // 72 staged cols + 1 pad
#define XS_SLICE  (8 * XS_COLS)             // 584 floats per wave slice
#define XS_TOTAL  (8 * XS_SLICE)            // 4672
#define TL_OFF    XS_TOTAL                  // tl[18][64] = 1152 floats
#define PART_OFF  (TL_OFF + OFFC * 64)      // part[8][18][64] = 9216 floats
#define SMEM_FLOATS (PART_OFF + 8 * OFFC * 64)   // 15040 floats = 60160 B
// ylds (64x256 bf16 = 32768 B) aliases part (36864 B), separated by barriers.

typedef __attribute__((ext_vector_type(8))) short bf16x8;
typedef __attribute__((ext_vector_type(4))) float f32x4;

__device__ __forceinline__ unsigned short f2bf(float f) {
  union { float f; unsigned u; } c; c.f = f;
  unsigned u = c.u;
  return (unsigned short)((u + 0x7FFFu + ((u >> 16) & 1u)) >> 16);  // RNE
}

__global__ void convert_wpw(const float* __restrict__ w_pw, unsigned short* __restrict__ wbf) {
  int i = blockIdx.x * 256 + threadIdx.x;
  if (i < COUT * CDIM) wbf[i] = f2bf(w_pw[i]);
}

// ---------------------------------------------------------------------------
// Mega-fused kernel: offset-conv + bilinear deform + depthwise + MFMA pointwise.
// Block = 512 threads = 8 waves; strip = 64 pixels (one h, w0..w0+63).
// ---------------------------------------------------------------------------
__global__ __launch_bounds__(512, 4)
void fused_all(const float* __restrict__ x, const float* __restrict__ w_off,
               const float* __restrict__ b_off, const float* __restrict__ w_deform,
               const unsigned short* __restrict__ wbf, float* __restrict__ out) {
  __shared__ float smem[SMEM_FLOATS];

  const int n  = blockIdx.z;
  const int h  = blockIdx.y;
  const int w0 = blockIdx.x * 64;
  const int tid = threadIdx.x;
  const int pl = tid & 63;          // pixel within strip (== lane)
  const int cg = tid >> 6;          // wave id
  const int w = w0 + pl;

  const float* xn = x + (size_t)n * CIN * HW;
  float* xsl  = smem + cg * XS_SLICE;   // wave-private staging slice
  float* tl   = smem + TL_OFF;          // [18][64] reduced offsets
  float* part = smem + PART_OFF;        // [8][18][64] partials
  unsigned short* ylds = (unsigned short*)(smem + PART_OFF);  // [64][256] alias

  // ==== phase 0: offset-conv partials (this wave's 8 channels) ====
  float ao[OFFC];
#pragma unroll
  for (int o = 0; o < OFFC; ++o) ao[o] = 0.f;

#pragma unroll 1
  for (int ci = 0; ci < 8; ++ci) {
    const int c = __builtin_amdgcn_readfirstlane(cg * 8 + ci);
    const float* xc = xn + (size_t)c * HW;
    // stage 3x66 (rows h-1..h+1, cols w0-1..w0+64), zero-filled at borders
    for (int i = pl; i < 198; i += 64) {
      int tr = i / 66, tc = i - tr * 66;
      int gy = h - 1 + tr, gx = w0 - 1 + tc;
      float v = 0.f;
      if (gy >= 0 && gy < HH && gx >= 0 && gx < WWID) v = xc[gy * WWID + gx];
      xsl[tr * 66 + tc] = v;    // wave-private: LDS ops in-order, no barrier
    }
    const float center = xsl[66 + pl + 1];
    float v[KK];
#pragma unroll
    for (int p = 0; p < KK; ++p)
      v[p] = xsl[(p / 3) * 66 + pl + (p % 3)] - center;   // v[4] == 0
#pragma unroll
    for (int o = 0; o < OFFC; ++o) {
      const float* wrow = w_off + ((size_t)o * CIN + c) * KK;  // SGPR base
      float a = ao[o];
#pragma unroll
      for (int p = 0; p < KK; ++p) {
        if (p == 4) continue;
        a += wrow[p] * v[p];
      }
      ao[o] = a;
    }
  }
#pragma unroll
  for (int o = 0; o < OFFC; ++o) part[(cg * OFFC + o) * 64 + pl] = ao[o];
  __syncthreads();

  // ==== cross-wave reduce -> tl[18][64] ====
  for (int idx = tid; idx < OFFC * 64; idx += 512) {
    const int o = idx >> 6, px = idx & 63;
    float s = b_off[o];
#pragma unroll
    for (int w8 = 0; w8 < 8; ++w8) s += part[(w8 * OFFC + o) * 64 + px];
    tl[o * 64 + px] = s;
  }
  __syncthreads();    // also fences part-reads before ylds (alias) writes

  // ==== tap precompute (per pixel pl) ====
  const int row0 = min(max(h - 3, 0), HH - 8);       // 8-row window, always valid
  const int col0 = min(max(w0 - 3, 0), WWID - 72);   // 72-col window, always valid
  const int hc  = h - row0;
  const int wcb = w0 - col0;
  unsigned pk[KK];
  float c00[KK], c01[KK], c10[KK], c11[KK];
  unsigned inmask = 0;
#pragma unroll
  for (int p = 0; p < KK; ++p) {
    const float dy = tl[(2 * p) * 64 + pl];
    const float dx = tl[(2 * p + 1) * 64 + pl];
    const float py  = dy + (float)(h + p / 3 - 1);
    const float pxx = dx + (float)(w + p % 3 - 1);
    const float fy = floorf(py), fx = floorf(pxx);
    const int y0 = (int)fy, x0 = (int)fx;
    const int y1 = y0 + 1,  x1 = x0 + 1;
    const float ay = py - fy, ax = pxx - fx;
    const bool vy0 = (y0 >= 0) && (y0 < HH), vy1 = (y1 >= 0) && (y1 < HH);
    const bool vx0 = (x0 >= 0) && (x0 < WWID), vx1 = (x1 >= 0) && (x1 < WWID);
    const int yc0 = min(max(y0, 0), HH - 1),  yc1 = min(max(y1, 0), HH - 1);
    const int xc0 = min(max(x0, 0), WWID - 1), xc1 = min(max(x1, 0), WWID - 1);
    const int ty0 = yc0 - row0, ty1 = yc1 - row0;
    const int tx0 = xc0 - col0, tx1 = xc1 - col0;
    if ((unsigned)ty0 < 8u && (unsigned)ty1 < 8u && (unsigned)tx0 < 72u && (unsigned)tx1 < 72u)
      inmask |= 1u << p;
    pk[p] = (unsigned)(ty0 & 255) | ((unsigned)(ty1 & 255) << 8)
          | ((unsigned)(tx0 & 255) << 16) | ((unsigned)(tx1 & 255) << 24);
    c00[p] = (vy0 && vx0) ? (1.f - ay) * (1.f - ax) : 0.f;
    c01[p] = (vy0 && vx1) ? (1.f - ay) * ax         : 0.f;
    c10[p] = (vy1 && vx0) ? ay * (1.f - ax)         : 0.f;
    c11[p] = (vy1 && vx1) ? ay * ax                 : 0.f;
  }

  // ==== phase 1: stage halo, LDS-gather bilinear, depthwise, -> ylds ====
#pragma unroll 1
  for (int ci = 0; ci < 8; ++ci) {
    const int c = __builtin_amdgcn_readfirstlane(cg * 8 + ci);
    const float* xc = xn + (size_t)c * HW;
#pragma unroll
    for (int k = 0; k < 9; ++k) {           // 576 = 9*64 halo elements
      const int i = pl + k * 64;
      const int r = i / 72, cl = i - r * 72;
      xsl[r * XS_COLS + cl] = xc[(row0 + r) * WWID + col0 + cl];
    }
    const float xcv = xsl[hc * XS_COLS + pl + wcb];
    float yd0 = 0.f, yd1 = 0.f, yd2 = 0.f, yd3 = 0.f;
#pragma unroll
    for (int p = 0; p < KK; ++p) {
      float samp;
      if (inmask & (1u << p)) {             // hot: in-tile LDS gather
        const unsigned k4 = pk[p];
        const int ty0 = k4 & 255, ty1 = (k4 >> 8) & 255;
        const int tx0 = (k4 >> 16) & 255, tx1 = k4 >> 24;
        samp = c00[p] * xsl[ty0 * XS_COLS + tx0] + c01[p] * xsl[ty0 * XS_COLS + tx1]
             + c10[p] * xsl[ty1 * XS_COLS + tx0] + c11[p] * xsl[ty1 * XS_COLS + tx1];
      } else {                              // cold: recompute + global gather
        const float dy = tl[(2 * p) * 64 + pl];
        const float dx = tl[(2 * p + 1) * 64 + pl];
        const float py  = dy + (float)(h + p / 3 - 1);
        const float pxx = dx + (float)(w + p % 3 - 1);
        const float fy = floorf(py), fx = floorf(pxx);
        const int y0 = (int)fy, x0 = (int)fx;
        const int yc0 = min(max(y0, 0), HH - 1),  yc1 = min(max(y0 + 1, 0), HH - 1);
        const int xc0 = min(max(x0, 0), WWID - 1), xc1 = min(max(x0 + 1, 0), WWID - 1);
        samp = c00[p] * xc[yc0 * WWID + xc0] + c01[p] * xc[yc0 * WWID + xc1]
             + c10[p] * xc[yc1 * WWID + xc0] + c11[p] * xc[yc1 * WWID + xc1];
      }
      const float s = samp - xcv;
      const float* wdp = w_deform + (size_t)(c * DDIM) * KK + p;  // SGPR base
      yd0 += wdp[0 * KK] * s;
      yd1 += wdp[1 * KK] * s;
      yd2 += wdp[2 * KK] * s;
      yd3 += wdp[3 * KK] * s;
    }
    const unsigned lo = (unsigned)f2bf(yd0) | ((unsigned)f2bf(yd1) << 16);
    const unsigned hi = (unsigned)f2bf(yd2) | ((unsigned)f2bf(yd3) << 16);
    const int ebase = (((c >> 1) ^ (pl & 7)) << 3) + (c & 1) * 4;  // 16B-chunk XOR swizzle
    *reinterpret_cast<uint2*>(&ylds[pl * CDIM + ebase]) = make_uint2(lo, hi);
  }
  __syncthreads();

  // ==== phase 2: MFMA pointwise; 8 waves -> 4(M) x 2(N) grid of 32x32 tiles ====
  const int l15 = tid & 15;
  const int kg  = (tid & 63) >> 4;
  const int Mb = (cg >> 1) * 32;
  const int Nb = (cg & 1) * 32;

  f32x4 acc[2][2];
#pragma unroll
  for (int mi = 0; mi < 2; ++mi)
#pragma unroll
    for (int ni = 0; ni < 2; ++ni)
      acc[mi][ni] = (f32x4){0.f, 0.f, 0.f, 0.f};

#pragma unroll
  for (int ks = 0; ks < 8; ++ks) {          // K = 256 in steps of 32
    bf16x8 bfr[2];
#pragma unroll
    for (int ni = 0; ni < 2; ++ni) {
      const int prow = Nb + ni * 16 + l15;
      const int chunk = ks * 4 + kg;
      const int eb = ((chunk ^ (prow & 7)) << 3);
      bfr[ni] = *reinterpret_cast<const bf16x8*>(&ylds[prow * CDIM + eb]);
    }
    bf16x8 afr[2];
#pragma unroll
    for (int mi = 0; mi < 2; ++mi) {
      const int o = Mb + mi * 16 + l15;
      afr[mi] = *reinterpret_cast<const bf16x8*>(wbf + (size_t)o * CDIM + ks * 32 + kg * 8);
    }
#pragma unroll
    for (int mi = 0; mi < 2; ++mi)
#pragma unroll
      for (int ni = 0; ni < 2; ++ni)
        acc[mi][ni] = __builtin_amdgcn_mfma_f32_16x16x32_bf16(afr[mi], bfr[ni], acc[mi][ni], 0, 0, 0);
  }

  // ==== epilogue: C/D layout col=lane&15, row=(lane>>4)*4+reg ====
  float* on = out + (size_t)n * COUT * HW;
#pragma unroll
  for (int mi = 0; mi < 2; ++mi) {
#pragma unroll
    for (int ni = 0; ni < 2; ++ni) {
      const int pcol = h * WWID + w0 + Nb + ni * 16 + l15;
#pragma unroll
      for (int reg = 0; reg < 4; ++reg) {
        const int o = Mb + mi * 16 + kg * 4 + reg;
        on[(size_t)o * HW + pcol] = acc[mi][ni][reg];
      }
    }
  }
}

// ---------------------------------------------------------------------------
extern "C" void kernel_launch(void* const* d_in, const int* in_sizes, int n_in,
                              void* d_out, int out_size, void* d_ws, size_t ws_size,
                              hipStream_t stream) {
  const float* x        = (const float*)d_in[0];
  const float* w_off    = (const float*)d_in[1];
  const float* b_off    = (const float*)d_in[2];
  const float* w_deform = (const float*)d_in[3];
  const float* w_pw     = (const float*)d_in[4];
  float* out = (float*)d_out;
  unsigned short* wbf = (unsigned short*)d_ws;   // 65536 B

  convert_wpw<<<dim3(COUT * CDIM / 256), dim3(256), 0, stream>>>(w_pw, wbf);
  fused_all<<<dim3(WWID / 64, HH, NN), dim3(512), 0, stream>>>(x, w_off, b_off, w_deform, wbf, out);
}